// Round 4
// baseline (399.222 us; speedup 1.0000x reference)
//
#include <hip/hip_runtime.h>
#include <math.h>

#define SEQ 512
#define NORD 256
#define MODES 32
#define KBIG (NORD*MODES*2)   // 16384
#define PI_F 3.14159265358979323846f

typedef _Float16 half8 __attribute__((ext_vector_type(8)));
typedef float floatx4 __attribute__((ext_vector_type(4)));
typedef unsigned int uint;

// Q tiled layout:  [kc 0..255][stt 0..31][tile 1024 halves], tile slot f = ks*64+kg8*16+m,
//   slot holds halves k64 = ks*32+kg8*8+(0..7) of row st = stt*16+m   (kg = kc*64 + k64)
// Wb tiled layout: [kc 0..255][ot 0..15][tile 1024 halves], same slot scheme with n = o&15.

// ---------------- f32 GEMM (32x32 tile, BK=64, reg prefetch) + Wb-builder rider ----

struct GJob {
  const float* A; const float* B; float* C; const float* scale_ptr;
  int M, N, lda, k0, k1, atomic;
};
struct GJobs {
  GJob j[6];
  const float* wwr[3]; const float* wwi[3];
  _Float16* Wt; int nGemm; int wb_i0; int wb_slab0;
};

__global__ __launch_bounds__(256) void gemm32_k(GJobs P) {
  int z = blockIdx.z;
  if (z >= P.nGemm) {
    // ---- Wb builder rider: one z-slice = one global i; 8 active blocks (by==0) ----
    if (blockIdx.y != 0) return;
    int ig = P.wb_i0 + (z - P.nGemm);          // 0..767
    int s = ig >> 8, i = ig & 255;
    const float* wr = P.wwr[s];
    const float* wi = P.wwi[s];
    uint* Wd = (uint*)(P.Wt + (size_t)(s - P.wb_slab0) * 4194304);
    int j = blockIdx.x * 256 + threadIdx.x;    // 0..2047
    int ot = j >> 7, loc = j & 127;
    int ks = loc >> 6, kg8 = (loc >> 4) & 3, on = loc & 15;
    int o = ot * 16 + on, k0 = ks * 16 + kg8 * 4;
    float4 wr4 = *(const float4*)&wr[(size_t)i * 8192 + o * 32 + k0];
    float4 wi4 = *(const float4*)&wi[(size_t)i * 8192 + o * 32 + k0];
    float wa[4] = {wr4.x, wr4.y, wr4.z, wr4.w};
    float wb[4] = {wi4.x, wi4.y, wi4.z, wi4.w};
    uint out[4];
    #pragma unroll
    for (int q = 0; q < 4; q++) {
      int k = k0 + q;
      float sn, cn; __sincosf((2.f * PI_F / 512.f) * (float)k, &sn, &cn);
      float g = ((k == 0) ? (1.f / 512.f) : (2.f / 512.f)) * 4096.f;
      float v0 = g * (cn * wa[q] + sn * wb[q]);
      float v1 = g * (sn * wa[q] - cn * wb[q]);
      _Float16 h0 = (_Float16)v0, h1 = (_Float16)v1;
      unsigned short u0, u1;
      __builtin_memcpy(&u0, &h0, 2); __builtin_memcpy(&u1, &h1, 2);
      out[q] = (uint)u0 | ((uint)u1 << 16);
    }
    *(uint4*)&Wd[((size_t)(i * 16 + ot)) * 512 + loc * 4] = *(uint4*)out;
    return;
  }
  GJob jb = P.j[z];
  int col0 = blockIdx.x * 32;
  int row0 = blockIdx.y * 32;
  if (row0 >= jb.M || col0 >= jb.N) return;
  __shared__ float As[64][34];
  __shared__ float Bs[64][36];
  int tid = threadIdx.x;
  int tx = tid & 15, ty = tid >> 4;
  const float* A = jb.A; const float* B = jb.B;
  int M = jb.M, N = jb.N, lda = jb.lda;
  int kcA = (tid & 15) * 4, rA = tid >> 4;
  int ccB = (tid & 7) * 4, kkB = tid >> 3;
  int gr0 = row0 + rA, gr1 = row0 + rA + 16;
  const float4 z4 = make_float4(0.f, 0.f, 0.f, 0.f);
  float4 a0, a1, b0, b1;
  {
    int kb = jb.k0;
    a0 = (gr0 < M) ? *(const float4*)&A[(size_t)gr0 * lda + kb + kcA] : z4;
    a1 = (gr1 < M) ? *(const float4*)&A[(size_t)gr1 * lda + kb + kcA] : z4;
    b0 = *(const float4*)&B[(size_t)(kb + kkB) * N + col0 + ccB];
    b1 = *(const float4*)&B[(size_t)(kb + kkB + 32) * N + col0 + ccB];
  }
  float acc00 = 0.f, acc01 = 0.f, acc10 = 0.f, acc11 = 0.f;
  for (int kb = jb.k0; kb < jb.k1; kb += 64) {
    As[kcA+0][rA] = a0.x; As[kcA+1][rA] = a0.y; As[kcA+2][rA] = a0.z; As[kcA+3][rA] = a0.w;
    As[kcA+0][rA+16] = a1.x; As[kcA+1][rA+16] = a1.y; As[kcA+2][rA+16] = a1.z; As[kcA+3][rA+16] = a1.w;
    *(float4*)&Bs[kkB][ccB] = b0;
    *(float4*)&Bs[kkB+32][ccB] = b1;
    __syncthreads();
    if (kb + 64 < jb.k1) {
      int kn = kb + 64;
      a0 = (gr0 < M) ? *(const float4*)&A[(size_t)gr0 * lda + kn + kcA] : z4;
      a1 = (gr1 < M) ? *(const float4*)&A[(size_t)gr1 * lda + kn + kcA] : z4;
      b0 = *(const float4*)&B[(size_t)(kn + kkB) * N + col0 + ccB];
      b1 = *(const float4*)&B[(size_t)(kn + kkB + 32) * N + col0 + ccB];
    }
    #pragma unroll
    for (int k = 0; k < 64; k++) {
      float2 av = *(float2*)&As[k][ty * 2];
      float2 bv = *(float2*)&Bs[k][tx * 2];
      acc00 += av.x * bv.x; acc01 += av.x * bv.y;
      acc10 += av.y * bv.x; acc11 += av.y * bv.y;
    }
    __syncthreads();
  }
  float sc = jb.scale_ptr ? *jb.scale_ptr : 1.f;
  int gr = row0 + ty * 2, gc = col0 + tx * 2;
  float v00 = acc00 * sc, v01 = acc01 * sc, v10 = acc10 * sc, v11 = acc11 * sc;
  if (jb.atomic) {
    if (gr < M)     { atomicAdd(&jb.C[(size_t)gr * N + gc], v00);     atomicAdd(&jb.C[(size_t)gr * N + gc + 1], v01); }
    if (gr + 1 < M) { atomicAdd(&jb.C[(size_t)(gr+1) * N + gc], v10); atomicAdd(&jb.C[(size_t)(gr+1) * N + gc + 1], v11); }
  } else {
    if (gr < M)     { jb.C[(size_t)gr * N + gc] = v00;     jb.C[(size_t)gr * N + gc + 1] = v01; }
    if (gr + 1 < M) { jb.C[(size_t)(gr+1) * N + gc] = v10; jb.C[(size_t)(gr+1) * N + gc + 1] = v11; }
  }
}

// ---------------- setup: transposes + kry init + zeroing + RevIN ----------------

__global__ __launch_bounds__(256) void setup_k(const float* A0, const float* A1, const float* A2,
                                               const float* B0, const float* B1, const float* B2,
                                               const float* E0, const float* E1, const float* E2,
                                               const float* x, const float* aw, const float* ab,
                                               float* R, float* Kry, float* Et, float* Z,
                                               float* F, float* stats) {
  long bid = blockIdx.x;
  int tid = threadIdx.x;
  if (bid < 768) {
    long idx = bid * 256 + tid;
    int scl = (int)(idx >> 16);
    int r = (int)(idx & 65535);
    int m = r >> 8, i2 = r & 255;
    const float* A = scl == 0 ? A0 : (scl == 1 ? A1 : A2);
    R[(size_t)scl * 2 * 65536 + (size_t)m * 256 + i2] = A[(size_t)i2 * 256 + m];
  } else if (bid < 2304) {
    long idx = (bid - 768) * 256 + tid;
    int scl = (int)(idx / 131072);
    int r = (int)(idx % 131072);
    int p = r >> 8, o = r & 255;
    const float* E; int rows;
    if (scl == 0) { E = E0; rows = 512; }
    else if (scl == 1) { E = E1; rows = 1024; }
    else { E = E2; rows = 2048; }
    int base = rows - 512;
    Et[(size_t)scl * 131072 + (size_t)o * 512 + p] = E[(size_t)(base + p) * 256 + o];
  } else if (bid < 2307) {
    int scl = (int)(bid - 2304);
    const float* B = scl == 0 ? B0 : (scl == 1 ? B1 : B2);
    Kry[(size_t)scl * 131072 + tid] = B[tid];
  } else if (bid < 4867) {
    long idx = (bid - 2307) * 256 + tid;
    if (idx < 655360) Z[idx] = 0.f;
  } else {
    int row = (int)(bid - 4867);            // b*32 + c
    int b = row >> 5, c = row & 31;
    const float* xp = x + (size_t)b * SEQ * 32 + c;
    float v0 = xp[(size_t)tid * 32];
    float v1 = xp[(size_t)(tid + 256) * 32];
    float s = v0 + v1, s2 = v0 * v0 + v1 * v1;
    for (int off = 32; off; off >>= 1) {
      s  += __shfl_down(s,  off, 64);
      s2 += __shfl_down(s2, off, 64);
    }
    __shared__ float ws1[4], ws2[4];
    __shared__ float mean_s, istd_s;
    int wid = tid >> 6, lane = tid & 63;
    if (lane == 0) { ws1[wid] = s; ws2[wid] = s2; }
    __syncthreads();
    if (tid == 0) {
      float t1 = ws1[0] + ws1[1] + ws1[2] + ws1[3];
      float t2 = ws2[0] + ws2[1] + ws2[2] + ws2[3];
      float mean = t1 / 512.f;
      float var = t2 / 512.f - mean * mean;
      float sd = sqrtf(var + 1e-5f);
      mean_s = mean; istd_s = 1.f / sd;
      stats[row] = mean; stats[512 + row] = sd;
    }
    __syncthreads();
    float w = aw[c], bb = ab[c];
    float m = mean_s, is = istd_s;
    F[(size_t)row * SEQ + tid]       = (v0 - m) * is * w + bb;
    F[(size_t)row * SEQ + tid + 256] = (v1 - m) * is * w + bb;
  }
}

// ---------------- qbuild phase A: chunk partials ----------------

__global__ __launch_bounds__(256) void qbuildA_k(const float* __restrict__ Kry,
                                                 float2* __restrict__ Pp, int s0) {
  int bg = blockIdx.x;
  int s = s0 + (bg >> 8);
  int r = bg & 255;
  int k = r & 31, c = r >> 5;
  const float* Kry_s = Kry + (size_t)s * 131072;
  float2* P = Pp + (size_t)s * 65536;
  int i = threadIdx.x;
  float ar = 0.f, ai = 0.f;
  const float step = 2.f * PI_F / 512.f;
  int m0 = c * 64;
  for (int mm = 0; mm < 64; mm++) {
    int m = m0 + mm;
    float kap = Kry_s[(size_t)m * 256 + i];
    float sn, cn; __sincosf(step * (float)((k * m) & 511), &sn, &cn);
    ar += kap * cn; ai -= kap * sn;
  }
  P[(size_t)(c * 32 + k) * 256 + i] = make_float2(ar, ai);
}

// ---------------- qbuild phase B: prefix + twiddle, writes TILED f16 Q ----------

__global__ __launch_bounds__(256) void qbuildB_k(const float* __restrict__ Kry,
                                                 const float2* __restrict__ Pp,
                                                 _Float16* __restrict__ Qf, int s0) {
  int bg = blockIdx.x;
  int slab = bg >> 8;
  int s = s0 + slab;
  int r = bg & 255;
  int ig = r & 31, c = r >> 5;
  const float* Kry_s = Kry + (size_t)s * 131072;
  const float2* P = Pp + (size_t)s * 65536;
  uint* Qd = (uint*)(Qf + (size_t)slab * 8388608);
  int tid = threadIdx.x;
  int k = tid & 31, il = tid >> 5;            // il 0..7 -> i = ig*8+il
  int i = ig * 8 + il;
  __shared__ __align__(16) uint buf[16 * 260]; // padded rows
  float ar = 0.f, ai = 0.f;
  for (int cp = 0; cp < c; cp++) {
    float2 p = P[(size_t)(cp * 32 + k) * 256 + i];
    ar += p.x; ai += p.y;
  }
  const float step = 2.f * PI_F / 512.f;
  int m0 = c * 64;
  int u = tid & 31, myil = tid >> 5;
  for (int mb = 0; mb < 64; mb += 16) {
    #pragma unroll
    for (int mm = 0; mm < 16; mm++) {
      int m = m0 + mb + mm;
      float kap = Kry_s[(size_t)m * 256 + i];
      float sn, cn; __sincosf(step * (float)((k * m) & 511), &sn, &cn);
      ar += kap * cn; ai -= kap * sn;
      int st = 511 - m;
      float sn2, cn2; __sincosf(step * (float)((k * st) & 511), &sn2, &cn2);
      float qr = ar * cn2 + ai * sn2;
      float qi = ai * cn2 - ar * sn2;
      qr = fminf(fmaxf(qr, -60000.f), 60000.f);
      qi = fminf(fmaxf(qi, -60000.f), 60000.f);
      _Float16 h0 = (_Float16)qr, h1 = (_Float16)qi;
      unsigned short u0, u1;
      __builtin_memcpy(&u0, &h0, 2); __builtin_memcpy(&u1, &h1, 2);
      buf[(st & 15) * 260 + il * 32 + k] = (uint)u0 | ((uint)u1 << 16);
    }
    __syncthreads();
    int stt = (511 - (m0 + mb)) >> 4;          // st-tile of this batch
    int kc = ig * 8 + myil;
    uint* tile = Qd + ((size_t)(kc * 32 + stt)) * 512;
    #pragma unroll
    for (int r4 = 0; r4 < 4; r4++) {
      int f = u * 4 + r4;
      int m = f & 15, kg8 = (f >> 4) & 3, ks = f >> 6;
      uint4 v = *(uint4*)&buf[m * 260 + myil * 32 + ks * 16 + kg8 * 4];
      *(uint4*)&tile[f * 4] = v;
    }
    __syncthreads();
  }
}

// ---------------- U = Q @ Wb, f16 MFMA, tiled layouts, split-K atomics ----------

__global__ __launch_bounds__(256) void umfma_k(const _Float16* __restrict__ Qf,
                                               const _Float16* __restrict__ Wt,
                                               float* __restrict__ U, int s0) {
  __shared__ __align__(16) uint Al_u[4096];
  __shared__ __align__(16) uint Bl_u[4096];
  int slab = blockIdx.z >> 4;
  int kslab = blockIdx.z & 15;
  int s = s0 + slab;
  const uint* Qt = (const uint*)(Qf + (size_t)slab * 8388608);
  const uint* Wu = (const uint*)(Wt + (size_t)slab * 4194304);
  float* Us = U + (size_t)s * 131072;
  int stt0 = blockIdx.x * 8;                 // m0 = bx*128
  int ot0 = blockIdx.y * 8;                  // n0 = by*128
  int m0 = blockIdx.x * 128, n0 = blockIdx.y * 128;
  int tid = threadIdx.x;
  int w = tid >> 6, lane = tid & 63;
  int quad = lane >> 4, lm = lane & 15;
  floatx4 acc[4][4];
  #pragma unroll
  for (int a = 0; a < 4; a++)
    #pragma unroll
    for (int b = 0; b < 4; b++) acc[a][b] = (floatx4)(0.f);
  int wmt = (w & 1) * 4, wnt = (w >> 1) * 4;
  uint4 qa[4], qb[4];
  {
    int kc = kslab * 16;
    const uint* qsrc = Qt + ((size_t)(kc * 32 + stt0)) * 512;
    const uint* wsrc = Wu + ((size_t)(kc * 16 + ot0)) * 512;
    #pragma unroll
    for (int r = 0; r < 4; r++) {
      qa[r] = *(const uint4*)&qsrc[(r * 256 + tid) * 4];
      qb[r] = *(const uint4*)&wsrc[(r * 256 + tid) * 4];
    }
  }
  for (int it = 0; it < 16; it++) {
    __syncthreads();
    #pragma unroll
    for (int r = 0; r < 4; r++) {
      *(uint4*)&Al_u[(r * 256 + tid) * 4] = qa[r];
      *(uint4*)&Bl_u[(r * 256 + tid) * 4] = qb[r];
    }
    __syncthreads();
    if (it < 15) {
      int kc = kslab * 16 + it + 1;
      const uint* qsrc = Qt + ((size_t)(kc * 32 + stt0)) * 512;
      const uint* wsrc = Wu + ((size_t)(kc * 16 + ot0)) * 512;
      #pragma unroll
      for (int r = 0; r < 4; r++) {
        qa[r] = *(const uint4*)&qsrc[(r * 256 + tid) * 4];
        qb[r] = *(const uint4*)&wsrc[(r * 256 + tid) * 4];
      }
    }
    #pragma unroll
    for (int ks = 0; ks < 2; ks++) {
      half8 af[4], bf[4];
      #pragma unroll
      for (int t = 0; t < 4; t++) {
        af[t] = *(half8*)((_Float16*)Al_u + ((wmt + t) * 1024 + ks * 512 + lane * 8));
        bf[t] = *(half8*)((_Float16*)Bl_u + ((wnt + t) * 1024 + ks * 512 + lane * 8));
      }
      #pragma unroll
      for (int mi = 0; mi < 4; mi++)
        #pragma unroll
        for (int ni = 0; ni < 4; ni++)
          acc[mi][ni] = __builtin_amdgcn_mfma_f32_16x16x32_f16(af[mi], bf[ni], acc[mi][ni], 0, 0, 0);
    }
  }
  #pragma unroll
  for (int mi = 0; mi < 4; mi++) {
    int gr0 = m0 + wmt * 16 + mi * 16 + quad * 4;
    #pragma unroll
    for (int ni = 0; ni < 4; ni++) {
      int gc = n0 + wnt * 16 + ni * 16 + lm;
      #pragma unroll
      for (int r = 0; r < 4; r++)
        atomicAdd(&Us[(size_t)(gr0 + r) * 256 + gc], acc[mi][ni][r] * (1.f / 4096.f));
    }
  }
}

// ---------------- fused y0 = F @ Ttot + denorm + channel projection --------------

__global__ __launch_bounds__(256) void y0final_k(const float* __restrict__ F,
                                                 const float* __restrict__ Ttot,
                                                 const float* __restrict__ stats,
                                                 const float* __restrict__ aw,
                                                 const float* __restrict__ ab,
                                                 const float* __restrict__ mlp_b,
                                                 const float* __restrict__ pw,
                                                 const float* __restrict__ pb,
                                                 float* __restrict__ out) {
  __shared__ float As[64][34];
  __shared__ float Bs[64][36];
  __shared__ float ys[32][33];
  __shared__ float pws[1024];
  int bxp = blockIdx.x;      // p block
  int b = blockIdx.y;        // batch
  int row0 = b * 32, col0 = bxp * 32;
  int tid = threadIdx.x;
  for (int t = tid; t < 1024; t += 256) pws[t] = pw[t];
  int tx = tid & 15, ty = tid >> 4;
  int kcA = (tid & 15) * 4, rA = tid >> 4;
  int ccB = (tid & 7) * 4, kkB = tid >> 3;
  int gr0 = row0 + rA, gr1 = row0 + rA + 16;
  float4 a0, a1, b0, b1;
  a0 = *(const float4*)&F[(size_t)gr0 * 512 + kcA];
  a1 = *(const float4*)&F[(size_t)gr1 * 512 + kcA];
  b0 = *(const float4*)&Ttot[(size_t)kkB * 512 + col0 + ccB];
  b1 = *(const float4*)&Ttot[(size_t)(kkB + 32) * 512 + col0 + ccB];
  float acc00 = 0.f, acc01 = 0.f, acc10 = 0.f, acc11 = 0.f;
  for (int kb = 0; kb < 512; kb += 64) {
    As[kcA+0][rA] = a0.x; As[kcA+1][rA] = a0.y; As[kcA+2][rA] = a0.z; As[kcA+3][rA] = a0.w;
    As[kcA+0][rA+16] = a1.x; As[kcA+1][rA+16] = a1.y; As[kcA+2][rA+16] = a1.z; As[kcA+3][rA+16] = a1.w;
    *(float4*)&Bs[kkB][ccB] = b0;
    *(float4*)&Bs[kkB+32][ccB] = b1;
    __syncthreads();
    if (kb + 64 < 512) {
      int kn = kb + 64;
      a0 = *(const float4*)&F[(size_t)gr0 * 512 + kn + kcA];
      a1 = *(const float4*)&F[(size_t)gr1 * 512 + kn + kcA];
      b0 = *(const float4*)&Ttot[(size_t)(kn + kkB) * 512 + col0 + ccB];
      b1 = *(const float4*)&Ttot[(size_t)(kn + kkB + 32) * 512 + col0 + ccB];
    }
    #pragma unroll
    for (int k = 0; k < 64; k++) {
      float2 av = *(float2*)&As[k][ty * 2];
      float2 bv = *(float2*)&Bs[k][tx * 2];
      acc00 += av.x * bv.x; acc01 += av.x * bv.y;
      acc10 += av.y * bv.x; acc11 += av.y * bv.y;
    }
    __syncthreads();
  }
  // denorm into ys
  float mb0 = mlp_b[0];
  {
    int c0 = ty * 2, c1 = ty * 2 + 1;
    int r0g = row0 + c0, r1g = row0 + c1;
    float mean0 = stats[r0g], sd0 = stats[512 + r0g];
    float mean1 = stats[r1g], sd1 = stats[512 + r1g];
    float q0 = sd0 / (aw[c0] + 1e-10f), q1 = sd1 / (aw[c1] + 1e-10f);
    float o0 = mean0 - (ab[c0] - mb0) * q0, o1 = mean1 - (ab[c1] - mb0) * q1;
    ys[c0][tx * 2]     = acc00 * q0 + o0;
    ys[c0][tx * 2 + 1] = acc01 * q0 + o0;
    ys[c1][tx * 2]     = acc10 * q1 + o1;
    ys[c1][tx * 2 + 1] = acc11 * q1 + o1;
  }
  __syncthreads();
  int p = tid >> 3, co0 = (tid & 7) * 4;
  float4 facc = *(const float4*)&pb[co0];
  #pragma unroll
  for (int cc = 0; cc < 32; cc++) {
    float f = ys[cc][p];
    float4 pw4 = *(float4*)&pws[cc * 32 + co0];
    facc.x += f * pw4.x; facc.y += f * pw4.y; facc.z += f * pw4.z; facc.w += f * pw4.w;
  }
  *(float4*)&out[(size_t)b * 16384 + (size_t)(col0 + p) * 32 + co0] = facc;
}

// ---------------- launch ----------------

extern "C" void kernel_launch(void* const* d_in, const int* in_sizes, int n_in,
                              void* d_out, int out_size, void* d_ws, size_t ws_size,
                              hipStream_t stream) {
  const float* x_enc = (const float*)d_in[0];
  const float* aw = (const float*)d_in[4];
  const float* ab = (const float*)d_in[5];
  const float* wr[3] = {(const float*)d_in[6], (const float*)d_in[8], (const float*)d_in[10]};
  const float* wi[3] = {(const float*)d_in[7], (const float*)d_in[9], (const float*)d_in[11]};
  const float* mlp_w = (const float*)d_in[12];
  const float* mlp_b = (const float*)d_in[13];
  const float* proj_w = (const float*)d_in[14];
  const float* proj_b = (const float*)d_in[15];
  const float* Am[3]  = {(const float*)d_in[16], (const float*)d_in[19], (const float*)d_in[22]};
  const float* Bv[3]  = {(const float*)d_in[17], (const float*)d_in[20], (const float*)d_in[23]};
  const float* Em[3]  = {(const float*)d_in[18], (const float*)d_in[21], (const float*)d_in[24]};

  float* w = (float*)d_ws;
  float* F     = w; w += 512 * 512;
  float* stats = w; w += 1024;
  float* Kry   = w; w += 3 * 512 * 256;
  float* R     = w; w += 3 * 2 * 65536;
  float* U     = w; w += 3 * 512 * 256;   // U and Ttot contiguous (zeroed together)
  float* Ttot  = w; w += 512 * 512;
  float* Et    = w; w += 3 * 256 * 512;
  float* Pp    = w; w += 3 * 65536 * 2;
  _Float16* Qf = (_Float16*)w;

  size_t base_bytes = (size_t)((char*)Qf - (char*)d_ws);
  size_t slab_bytes = (size_t)(8388608 + 4194304) * 2;
  int nS = (ws_size >= base_bytes + 3 * slab_bytes) ? 3 : 1;
  _Float16* Wb = Qf + (size_t)nS * 8388608;

  setup_k<<<5379, 256, 0, stream>>>(Am[0], Am[1], Am[2], Bv[0], Bv[1], Bv[2],
                                    Em[0], Em[1], Em[2], x_enc, aw, ab,
                                    R, Kry, Et, U, F, stats);

  // Krylov doubling; Wb-builder blocks ride each dispatch (batched mode only)
  int wb_done = 0;
  for (int j = 0; j < 9; j++) {
    GJobs P{};
    int M = 1 << j;
    int cur = j & 1;
    int nz = 0;
    for (int s = 0; s < 3; s++) {
      float* Ks = Kry + (size_t)s * 131072;
      float* Rj = R + (size_t)s * 131072 + (size_t)cur * 65536;
      float* Rn = R + (size_t)s * 131072 + (size_t)(1 - cur) * 65536;
      P.j[nz++] = {Ks, Rj, Ks + (size_t)M * 256, nullptr, M, 256, 256, 0, 256, 0};
      if (j < 8) P.j[nz++] = {Rj, Rj, Rn, nullptr, 256, 256, 256, 0, 256, 0};
    }
    P.nGemm = nz;
    int wb_cnt = 0;
    if (nS == 3) {
      wb_cnt = (j < 8) ? 86 : (768 - 86 * 8);
      P.wwr[0] = wr[0]; P.wwr[1] = wr[1]; P.wwr[2] = wr[2];
      P.wwi[0] = wi[0]; P.wwi[1] = wi[1]; P.wwi[2] = wi[2];
      P.Wt = Wb; P.wb_i0 = wb_done; P.wb_slab0 = 0;
      wb_done += wb_cnt;
    }
    gemm32_k<<<dim3(8, 8, nz + wb_cnt), 256, 0, stream>>>(P);
  }

  if (nS == 3) {
    qbuildA_k<<<768, 256, 0, stream>>>(Kry, (float2*)Pp, 0);
    qbuildB_k<<<768, 256, 0, stream>>>(Kry, (const float2*)Pp, Qf, 0);
    umfma_k<<<dim3(4, 2, 48), 256, 0, stream>>>(Qf, Wb, U, 0);
  } else {
    for (int s = 0; s < 3; s++) {
      GJobs P{};
      P.nGemm = 0;
      P.wwr[0] = wr[0]; P.wwr[1] = wr[1]; P.wwr[2] = wr[2];
      P.wwi[0] = wi[0]; P.wwi[1] = wi[1]; P.wwi[2] = wi[2];
      P.Wt = Wb; P.wb_i0 = s * 256; P.wb_slab0 = s;
      gemm32_k<<<dim3(8, 1, 256), 256, 0, stream>>>(P);
      qbuildA_k<<<256, 256, 0, stream>>>(Kry, (float2*)Pp, s);
      qbuildB_k<<<256, 256, 0, stream>>>(Kry, (const float2*)Pp, Qf, s);
      umfma_k<<<dim3(4, 2, 16), 256, 0, stream>>>(Qf, Wb, U, s);
    }
  }

  // Ttot += mlp_w[s] * U_s @ Et_s
  {
    GJobs P{};
    for (int s = 0; s < 3; s++)
      P.j[s] = {U + (size_t)s * 131072, Et + (size_t)s * 131072, Ttot,
                mlp_w + s, 512, 512, 256, 0, 256, 1};
    P.nGemm = 3;
    gemm32_k<<<dim3(16, 16, 3), 256, 0, stream>>>(P);
  }

  // y0 = F @ Ttot fused with denorm + projection
  y0final_k<<<dim3(16, 16), 256, 0, stream>>>(F, Ttot, stats, aw, ab, mlp_b,
                                              proj_w, proj_b, (float*)d_out);
}